// Round 11
// baseline (1349.847 us; speedup 1.0000x reference)
//
#include <hip/hip_runtime.h>

#define N_NODES 100000
#define N_EDGES 1600000
#define K_DIM   200
#define C_DIM   64
#define EPS_BN  1e-5f
#define NB_SCAN ((N_NODES + 255) / 256)   // 391
#define MT      128                       // gemm rows per block
#define NKB     25                        // 200 / 8 k-blocks
#define SLICE_U ((size_t)N_NODES * 16)    // ushorts per 16-ch bf16 slice
#define NPX     12500                     // nodes per XCD range
#define BCAP    28672                     // pairs per (bucket,writer) segment

// clang ext_vector types: accepted by __builtin_nontemporal_load/store
typedef int   vi4 __attribute__((ext_vector_type(4)));
typedef float vf4 __attribute__((ext_vector_type(4)));

__device__ __forceinline__ ushort f2bf(float f) {
    unsigned u = __float_as_uint(f);
    u = (u + 0x7FFFu + ((u >> 16) & 1u)) >> 16;   // RNE
    return (ushort)u;
}

// ===================== GEMM: 128x64 tile -> pre-scaled bf16 4-slice xsp ====
__global__ __launch_bounds__(256) void k_gemm2(const float* __restrict__ x,
                                               const float* __restrict__ W,
                                               const float* __restrict__ dinv,
                                               ushort* __restrict__ xsp) {
    __shared__ float xT[8][MT];      // 4 KB
    __shared__ float Wt[8][C_DIM];   // 2 KB
    int tid = threadIdx.x;
    int tx = tid & 15;               // channels tx*4..tx*4+3
    int ty = tid >> 4;               // row octet
    int row0 = blockIdx.x * MT;

    int lrow = tid >> 1;
    int lk   = (tid & 1) * 4;
    int grow = row0 + lrow;
    if (grow > N_NODES - 1) grow = N_NODES - 1;
    const float* xp = x + (size_t)grow * K_DIM + lk;
    int wk = tid >> 4;
    int wc = (tid & 15) * 4;

    float acc[8][4];
    #pragma unroll
    for (int i = 0; i < 8; ++i)
        #pragma unroll
        for (int j = 0; j < 4; ++j) acc[i][j] = 0.f;

    float4 xr = *(const float4*)xp;
    float4 wr = {0,0,0,0};
    if (tid < 128) wr = *(const float4*)(W + wk * C_DIM + wc);

    for (int kb = 0; kb < NKB; ++kb) {
        xT[lk + 0][lrow] = xr.x;
        xT[lk + 1][lrow] = xr.y;
        xT[lk + 2][lrow] = xr.z;
        xT[lk + 3][lrow] = xr.w;
        if (tid < 128) *(float4*)&Wt[wk][wc] = wr;
        __syncthreads();
        if (kb < NKB - 1) {
            xr = *(const float4*)(xp + (kb + 1) * 8);
            if (tid < 128) wr = *(const float4*)(W + ((kb + 1) * 8 + wk) * C_DIM + wc);
        }
        #pragma unroll
        for (int k = 0; k < 8; ++k) {
            float4 xa = *(const float4*)&xT[k][ty * 8];
            float4 xb = *(const float4*)&xT[k][ty * 8 + 4];
            float4 wv = *(const float4*)&Wt[k][tx * 4];
            float xv[8] = {xa.x, xa.y, xa.z, xa.w, xb.x, xb.y, xb.z, xb.w};
            #pragma unroll
            for (int i = 0; i < 8; ++i) {
                acc[i][0] = fmaf(xv[i], wv.x, acc[i][0]);
                acc[i][1] = fmaf(xv[i], wv.y, acc[i][1]);
                acc[i][2] = fmaf(xv[i], wv.z, acc[i][2]);
                acc[i][3] = fmaf(xv[i], wv.w, acc[i][3]);
            }
        }
        __syncthreads();
    }
    int sl  = tx >> 2;                 // slice 0..3  (16 channels each)
    int pos = (tx & 3) * 4;            // ushort offset within slice row
    #pragma unroll
    for (int i = 0; i < 8; ++i) {
        int r = row0 + ty * 8 + i;
        if (r < N_NODES) {
            float dv = dinv[r];
            ushort4 o = {f2bf(acc[i][0] * dv), f2bf(acc[i][1] * dv),
                         f2bf(acc[i][2] * dv), f2bf(acc[i][3] * dv)};
            *(ushort4*)(xsp + (size_t)sl * SLICE_U + (size_t)r * 16 + pos) = o;
        }
    }
}

// ===================== phase A: bucket edges by dst range + degree count ===
// Wave-aggregated append into 64 segments [bucket k][writer-xcd w].
// Edge packed as (src<<14)|(dst-k*NPX): src<2^17, dloc<2^14 -> 31 bits.
__global__ __launch_bounds__(256) void k_bucket(
        const int* __restrict__ src, const int* __restrict__ dst,
        int* __restrict__ deg, int* __restrict__ bcnt,
        unsigned* __restrict__ bkt) {
    int lane = threadIdx.x & 63;
    int wx   = blockIdx.x & 7;            // writer XCD (round-robin dispatch)
    int tid0 = blockIdx.x * 256 + threadIdx.x;
    int stride = gridDim.x * 256;
    for (int e = tid0; e < N_EDGES; e += stride) {   // N_EDGES%64==0 -> wave-uniform
        int d = __builtin_nontemporal_load(dst + e);
        int s = __builtin_nontemporal_load(src + e);
        atomicAdd(&deg[d], 1);
        int bk = (unsigned)d / NPX;                  // 0..7
        unsigned v = ((unsigned)s << 14) | (unsigned)(d - bk * NPX);
        #pragma unroll
        for (int k = 0; k < 8; ++k) {
            unsigned long long m = __ballot(bk == k);
            if (m == 0ull) continue;                 // wave-uniform
            if (bk == k) {
                int leader = __ffsll(m) - 1;
                int cnt = __popcll(m);
                int base = 0;
                if (lane == leader) base = atomicAdd(&bcnt[k * 8 + wx], cnt);
                base = __shfl(base, leader);
                int pos = base + __popcll(m & ((1ull << lane) - 1ull));
                bkt[((size_t)k * 8 + wx) * BCAP + pos] = v;
            }
        }
    }
}

// ===================== scans (row_start, dinv) ============================
__global__ void k_scan_block(const int* __restrict__ deg, int* __restrict__ bsum) {
    __shared__ int ls[256];
    int i = blockIdx.x * 256 + threadIdx.x;
    ls[threadIdx.x] = (i < N_NODES) ? deg[i] : 0;
    __syncthreads();
    for (int off = 128; off > 0; off >>= 1) {
        if (threadIdx.x < off) ls[threadIdx.x] += ls[threadIdx.x + off];
        __syncthreads();
    }
    if (threadIdx.x == 0) bsum[blockIdx.x] = ls[0];
}

__global__ void k_scan_top(const int* __restrict__ bsum, int* __restrict__ boff) {
    __shared__ int ls[512];
    int v = (threadIdx.x < NB_SCAN) ? bsum[threadIdx.x] : 0;
    ls[threadIdx.x] = v;
    __syncthreads();
    for (int off = 1; off < 512; off <<= 1) {
        int t = (threadIdx.x >= off) ? ls[threadIdx.x - off] : 0;
        __syncthreads();
        ls[threadIdx.x] += t;
        __syncthreads();
    }
    if (threadIdx.x < NB_SCAN) boff[threadIdx.x] = ls[threadIdx.x] - v; // exclusive
}

__global__ void k_scan_write(const int* __restrict__ deg, const int* __restrict__ boff,
                             int* __restrict__ row_start, float* __restrict__ dinv) {
    __shared__ int ls[256];
    int i = blockIdx.x * 256 + threadIdx.x;
    int v = (i < N_NODES) ? deg[i] : 0;
    ls[threadIdx.x] = v;
    __syncthreads();
    for (int off = 1; off < 256; off <<= 1) {        // inclusive scan
        int t = (threadIdx.x >= off) ? ls[threadIdx.x - off] : 0;
        __syncthreads();
        ls[threadIdx.x] += t;
        __syncthreads();
    }
    if (i < N_NODES) {
        row_start[i] = boff[blockIdx.x] + ls[threadIdx.x] - v;  // exclusive
        dinv[i] = rsqrtf((float)v + 1.0f);                      // +1 self loop
    }
    if (i == N_NODES - 1) row_start[N_NODES] = N_EDGES;
}

// ===================== phase B: drain bucket k on XCD k -> csr range k =====
// Bucket stream (800KB) + csr range (800KB) + cursor (50KB) all L2-resident:
// csr lines fill completely and write back once.
__global__ __launch_bounds__(256) void k_fillb(
        const unsigned* __restrict__ bkt, const int* __restrict__ bcnt,
        const int* __restrict__ row_start, int* __restrict__ cursor,
        int* __restrict__ csr) {
    int k   = blockIdx.x & 7;
    int lb  = blockIdx.x >> 3;
    int nlb = gridDim.x >> 3;
    int lo  = k * NPX;
    for (int w = 0; w < 8; ++w) {
        int n = bcnt[k * 8 + w];
        const unsigned* seg = bkt + ((size_t)k * 8 + w) * BCAP;
        for (int i = lb * 256 + threadIdx.x; i < n; i += nlb * 256) {
            unsigned v = seg[i];
            int s = v >> 14;
            int d = lo + (int)(v & 16383u);
            int p = atomicAdd(&cursor[d], 1);
            csr[row_start[d] + p] = s;
        }
    }
}

// ===================== gather: lane = node, bf16 slice, fused BN stats =====
#define UNPK0(u, k) { acc[k] = __uint_as_float((u) << 16); \
                      acc[k+1] = __uint_as_float((u) & 0xFFFF0000u); }
#define UNPKA(u, k) { acc[k] += __uint_as_float((u) << 16); \
                      acc[k+1] += __uint_as_float((u) & 0xFFFF0000u); }

__global__ __launch_bounds__(256) void k_gath4(
        const int* __restrict__ csr, const int* __restrict__ row_start,
        const float* __restrict__ dinv, const ushort* __restrict__ xsp,
        const float* __restrict__ b, float* __restrict__ hp2,
        float* __restrict__ stats) {
    int tid  = threadIdx.x;
    int lane = tid & 63;
    int widx = tid >> 6;
    int bid  = blockIdx.x;
    int slice = (bid & 7) >> 1;
    int chunk = ((bid >> 3) * 2 + (bid & 1)) * 4 + widx;
    int nchunks = (gridDim.x >> 3) * 8;            // waves per slice
    const ushort* xs = xsp + (size_t)slice * SLICE_U;
    const float*  bs = b + slice * 16;
    float s1[16], s2[16];
    #pragma unroll
    for (int i = 0; i < 16; ++i) { s1[i] = 0.f; s2[i] = 0.f; }

    for (int n0 = chunk * 64; n0 < N_NODES; n0 += nchunks * 64) {
        int n = n0 + lane;
        bool act = n < N_NODES;
        int beg = 0, end = 0;
        float dn = 0.f;
        float acc[16];
        if (act) {
            beg = __builtin_nontemporal_load(row_start + n);
            end = __builtin_nontemporal_load(row_start + n + 1);
            dn  = __builtin_nontemporal_load(dinv + n);
            const uint4* rp = (const uint4*)(xs + (size_t)n * 16);  // self row
            uint4 a = rp[0], c = rp[1];
            UNPK0(a.x, 0)  UNPK0(a.y, 2)  UNPK0(a.z, 4)  UNPK0(a.w, 6)
            UNPK0(c.x, 8)  UNPK0(c.y, 10) UNPK0(c.z, 12) UNPK0(c.w, 14)
        } else {
            #pragma unroll
            for (int i = 0; i < 16; ++i) acc[i] = 0.f;
        }
        int j = beg;
        for (; j + 2 <= end; j += 2) {             // 2 rows in flight
            int s0  = csr[j];
            int s1e = csr[j + 1];
            const uint4* p0 = (const uint4*)(xs + (size_t)s0 * 16);
            const uint4* p1 = (const uint4*)(xs + (size_t)s1e * 16);
            uint4 a0 = p0[0], c0 = p0[1];
            uint4 a1 = p1[0], c1 = p1[1];
            UNPKA(a0.x, 0)  UNPKA(a0.y, 2)  UNPKA(a0.z, 4)  UNPKA(a0.w, 6)
            UNPKA(c0.x, 8)  UNPKA(c0.y, 10) UNPKA(c0.z, 12) UNPKA(c0.w, 14)
            UNPKA(a1.x, 0)  UNPKA(a1.y, 2)  UNPKA(a1.z, 4)  UNPKA(a1.w, 6)
            UNPKA(c1.x, 8)  UNPKA(c1.y, 10) UNPKA(c1.z, 12) UNPKA(c1.w, 14)
        }
        if (j < end) {
            int s0 = csr[j];
            const uint4* p0 = (const uint4*)(xs + (size_t)s0 * 16);
            uint4 a0 = p0[0], c0 = p0[1];
            UNPKA(a0.x, 0)  UNPKA(a0.y, 2)  UNPKA(a0.z, 4)  UNPKA(a0.w, 6)
            UNPKA(c0.x, 8)  UNPKA(c0.y, 10) UNPKA(c0.z, 12) UNPKA(c0.w, 14)
        }
        if (act) {
            #pragma unroll
            for (int sub = 0; sub < 4; ++sub) {
                vf4 hv;
                hv.x = fmaxf(fmaf(dn, acc[4*sub+0], bs[4*sub+0]), 0.f);
                hv.y = fmaxf(fmaf(dn, acc[4*sub+1], bs[4*sub+1]), 0.f);
                hv.z = fmaxf(fmaf(dn, acc[4*sub+2], bs[4*sub+2]), 0.f);
                hv.w = fmaxf(fmaf(dn, acc[4*sub+3], bs[4*sub+3]), 0.f);
                __builtin_nontemporal_store(hv,
                    (vf4*)(hp2 + ((size_t)(slice * 4 + sub) * N_NODES + n) * 4));
                s1[4*sub+0] += hv.x; s2[4*sub+0] = fmaf(hv.x, hv.x, s2[4*sub+0]);
                s1[4*sub+1] += hv.y; s2[4*sub+1] = fmaf(hv.y, hv.y, s2[4*sub+1]);
                s1[4*sub+2] += hv.z; s2[4*sub+2] = fmaf(hv.z, hv.z, s2[4*sub+2]);
                s1[4*sub+3] += hv.w; s2[4*sub+3] = fmaf(hv.w, hv.w, s2[4*sub+3]);
            }
        }
    }

    // wave reduce 32 values, then block reduce via LDS, then atomics
    __shared__ float red[4][32];
    #pragma unroll
    for (int i = 0; i < 16; ++i) {
        float a = s1[i], c = s2[i];
        #pragma unroll
        for (int m = 1; m <= 32; m <<= 1) {
            a += __shfl_xor(a, m);
            c += __shfl_xor(c, m);
        }
        if (lane == 0) { red[widx][i] = a; red[widx][16 + i] = c; }
    }
    __syncthreads();
    if (tid < 32) {
        float v = red[0][tid] + red[1][tid] + red[2][tid] + red[3][tid];
        int ch = slice * 16 + (tid & 15);
        unsafeAtomicAdd(&stats[(tid >> 4) * 64 + ch], v);
    }
}

// ---------------- BN scale/shift precompute (64 threads) -------------------
__global__ void k_scale(const float* __restrict__ stats_in, const float* __restrict__ bnw,
                        const float* __restrict__ bnb, float* __restrict__ scsh) {
    int c = threadIdx.x;   // 0..63
    float mean = stats_in[c] * (1.0f / N_NODES);
    float var  = stats_in[64 + c] * (1.0f / N_NODES) - mean * mean;
    float sc = rsqrtf(var + EPS_BN) * bnw[c];
    scsh[c]      = sc;
    scsh[64 + c] = bnb[c] - mean * sc;
}

// ---------------- BN apply + un-permute ------------------------------------
__global__ __launch_bounds__(256) void k_final_p(
        const float* __restrict__ hp2, const float* __restrict__ scsh,
        float* __restrict__ out) {
    int tid = blockIdx.x * 256 + threadIdx.x;   // over N_NODES*16
    if (tid >= N_NODES * 16) return;
    int q = tid & 15;
    int n = tid >> 4;
    vf4 v  = __builtin_nontemporal_load((const vf4*)hp2 + (size_t)q * N_NODES + n);
    vf4 sc = *(const vf4*)(scsh + q * 4);
    vf4 sh = *(const vf4*)(scsh + 64 + q * 4);
    vf4 o = v * sc + sh;
    __builtin_nontemporal_store(o, (vf4*)out + tid);
}

// ===========================================================================
extern "C" void kernel_launch(void* const* d_in, const int* in_sizes, int n_in,
                              void* d_out, int out_size, void* d_ws, size_t ws_size,
                              hipStream_t stream) {
    const float* x   = (const float*)d_in[0];
    const int*   ei  = (const int*)d_in[1];
    const float* W   = (const float*)d_in[2];
    const float* b   = (const float*)d_in[3];
    const float* bnw = (const float*)d_in[4];
    const float* bnb = (const float*)d_in[5];
    float* out = (float*)d_out;

    const int* src = ei;
    const int* dst = ei + N_EDGES;
    char* ws = (char*)d_ws;

    const size_t SZ_I = 400128;                 // 100000*4 padded
    const size_t OFF_CUR  = SZ_I;
    const size_t OFF_STAT = 2 * SZ_I;           // 512B stat sums
    const size_t OFF_BCNT = 2 * SZ_I + 512;     // 256B (64 counters)
    const size_t OFF_SCSH = 2 * SZ_I + 768;     // 512B scale/shift
    const size_t OFF_DINV = 2 * SZ_I + 1280;
    const size_t OFF_ROW  = OFF_DINV + SZ_I;
    const size_t OFF_BSUM = OFF_ROW + SZ_I;
    const size_t OFF_BOFF = OFF_BSUM + 2048;
    const size_t OFF_CSR  = OFF_BOFF + 2048;
    const size_t OFF_H    = OFF_CSR + (size_t)N_EDGES * 4;
    // buckets alias the hp2 region: dead before k_gath4 writes hp2
    const size_t OFF_BKT  = OFF_H;
    const size_t ZERO_B   = 2 * SZ_I + 768;     // deg, cursor, stats, bcnt

    ushort* xsp = (ushort*)out;   // 12.8 MB bf16 slice-packed, dead after k_gath4
    const int GEMM_GRID = (N_NODES + MT - 1) / MT;   // 782

    int*      deg       = (int*)ws;
    int*      cursor    = (int*)(ws + OFF_CUR);
    float*    stats     = (float*)(ws + OFF_STAT);
    int*      bcnt      = (int*)(ws + OFF_BCNT);
    float*    scsh      = (float*)(ws + OFF_SCSH);
    float*    dinv      = (float*)(ws + OFF_DINV);
    int*      row_start = (int*)(ws + OFF_ROW);
    int*      bsum      = (int*)(ws + OFF_BSUM);
    int*      boff      = (int*)(ws + OFF_BOFF);
    int*      csr       = (int*)(ws + OFF_CSR);
    unsigned* bkt       = (unsigned*)(ws + OFF_BKT);
    float*    hp2       = (float*)(ws + OFF_H);

    hipMemsetAsync(d_ws, 0, ZERO_B, stream);  // deg, cursor, stats, bcnt

    k_bucket    <<<2048, 256, 0, stream>>>(src, dst, deg, bcnt, bkt);
    k_scan_block<<<NB_SCAN, 256, 0, stream>>>(deg, bsum);
    k_scan_top  <<<1, 512, 0, stream>>>(bsum, boff);
    k_scan_write<<<NB_SCAN, 256, 0, stream>>>(deg, boff, row_start, dinv);
    k_fillb     <<<2048, 256, 0, stream>>>(bkt, bcnt, row_start, cursor, csr);
    k_gemm2     <<<GEMM_GRID, 256, 0, stream>>>(x, W, dinv, xsp);
    k_gath4     <<<1568, 256, 0, stream>>>(csr, row_start, dinv, xsp, b, hp2, stats);
    k_scale     <<<1, 64, 0, stream>>>(stats, bnw, bnb, scsh);
    k_final_p   <<<(N_NODES * 16 + 255) / 256, 256, 0, stream>>>(hp2, scsh, out);
    (void)ws_size;
}

// Round 12
// 319.849 us; speedup vs baseline: 4.2203x; 4.2203x over previous
//
#include <hip/hip_runtime.h>

#define N_NODES 100000
#define N_EDGES 1600000
#define K_DIM   200
#define C_DIM   64
#define EPS_BN  1e-5f
#define NB_SCAN ((N_NODES + 255) / 256)   // 391
#define MT      128                       // gemm rows per block
#define NKB     25                        // 200 / 8 k-blocks
#define SLICE_U ((size_t)N_NODES * 16)    // ushorts per 16-ch bf16 slice
#define NPX     12500                     // nodes per XCD range
#define NBLK    2048                      // hist/scatter grid (must match)

// clang ext_vector types: accepted by __builtin_nontemporal_load/store
typedef int   vi4 __attribute__((ext_vector_type(4)));
typedef float vf4 __attribute__((ext_vector_type(4)));

__device__ __forceinline__ ushort f2bf(float f) {
    unsigned u = __float_as_uint(f);
    u = (u + 0x7FFFu + ((u >> 16) & 1u)) >> 16;   // RNE
    return (ushort)u;
}

// ===================== GEMM: 128x64 tile -> pre-scaled bf16 4-slice xsp ====
__global__ __launch_bounds__(256) void k_gemm2(const float* __restrict__ x,
                                               const float* __restrict__ W,
                                               const float* __restrict__ dinv,
                                               ushort* __restrict__ xsp) {
    __shared__ float xT[8][MT];      // 4 KB
    __shared__ float Wt[8][C_DIM];   // 2 KB
    int tid = threadIdx.x;
    int tx = tid & 15;               // channels tx*4..tx*4+3
    int ty = tid >> 4;               // row octet
    int row0 = blockIdx.x * MT;

    int lrow = tid >> 1;
    int lk   = (tid & 1) * 4;
    int grow = row0 + lrow;
    if (grow > N_NODES - 1) grow = N_NODES - 1;
    const float* xp = x + (size_t)grow * K_DIM + lk;
    int wk = tid >> 4;
    int wc = (tid & 15) * 4;

    float acc[8][4];
    #pragma unroll
    for (int i = 0; i < 8; ++i)
        #pragma unroll
        for (int j = 0; j < 4; ++j) acc[i][j] = 0.f;

    float4 xr = *(const float4*)xp;
    float4 wr = {0,0,0,0};
    if (tid < 128) wr = *(const float4*)(W + wk * C_DIM + wc);

    for (int kb = 0; kb < NKB; ++kb) {
        xT[lk + 0][lrow] = xr.x;
        xT[lk + 1][lrow] = xr.y;
        xT[lk + 2][lrow] = xr.z;
        xT[lk + 3][lrow] = xr.w;
        if (tid < 128) *(float4*)&Wt[wk][wc] = wr;
        __syncthreads();
        if (kb < NKB - 1) {
            xr = *(const float4*)(xp + (kb + 1) * 8);
            if (tid < 128) wr = *(const float4*)(W + ((kb + 1) * 8 + wk) * C_DIM + wc);
        }
        #pragma unroll
        for (int k = 0; k < 8; ++k) {
            float4 xa = *(const float4*)&xT[k][ty * 8];
            float4 xb = *(const float4*)&xT[k][ty * 8 + 4];
            float4 wv = *(const float4*)&Wt[k][tx * 4];
            float xv[8] = {xa.x, xa.y, xa.z, xa.w, xb.x, xb.y, xb.z, xb.w};
            #pragma unroll
            for (int i = 0; i < 8; ++i) {
                acc[i][0] = fmaf(xv[i], wv.x, acc[i][0]);
                acc[i][1] = fmaf(xv[i], wv.y, acc[i][1]);
                acc[i][2] = fmaf(xv[i], wv.z, acc[i][2]);
                acc[i][3] = fmaf(xv[i], wv.w, acc[i][3]);
            }
        }
        __syncthreads();
    }
    int sl  = tx >> 2;                 // slice 0..3  (16 channels each)
    int pos = (tx & 3) * 4;            // ushort offset within slice row
    #pragma unroll
    for (int i = 0; i < 8; ++i) {
        int r = row0 + ty * 8 + i;
        if (r < N_NODES) {
            float dv = dinv[r];
            ushort4 o = {f2bf(acc[i][0] * dv), f2bf(acc[i][1] * dv),
                         f2bf(acc[i][2] * dv), f2bf(acc[i][3] * dv)};
            *(ushort4*)(xsp + (size_t)sl * SLICE_U + (size_t)r * 16 + pos) = o;
        }
    }
}

// ===================== pass A: per-block dst-range histogram + deg count ===
__global__ __launch_bounds__(256) void k_hist8(
        const int* __restrict__ dst, int* __restrict__ deg,
        int* __restrict__ bchist) {
    __shared__ int h[8];
    if (threadIdx.x < 8) h[threadIdx.x] = 0;
    __syncthreads();
    int i0 = blockIdx.x * 256 + threadIdx.x;
    int stride = NBLK * 256;
    for (int i = i0; i < N_EDGES / 4; i += stride) {
        vi4 d = __builtin_nontemporal_load((const vi4*)dst + i);
        atomicAdd(&deg[d.x], 1); atomicAdd(&h[(unsigned)d.x / NPX], 1);
        atomicAdd(&deg[d.y], 1); atomicAdd(&h[(unsigned)d.y / NPX], 1);
        atomicAdd(&deg[d.z], 1); atomicAdd(&h[(unsigned)d.z / NPX], 1);
        atomicAdd(&deg[d.w], 1); atomicAdd(&h[(unsigned)d.w / NPX], 1);
    }
    __syncthreads();
    if (threadIdx.x < 8) bchist[blockIdx.x * 8 + threadIdx.x] = h[threadIdx.x];
}

// ===================== scan of [NBLK][8] histogram (1 block) ===============
__global__ __launch_bounds__(256) void k_scanb(
        const int* __restrict__ bchist, int* __restrict__ bko,
        int* __restrict__ bbase) {
    __shared__ int ls[256];
    __shared__ int kbase;
    int t = threadIdx.x;
    if (t == 0) kbase = 0;
    __syncthreads();
    for (int k = 0; k < 8; ++k) {
        int local[8];
        int s = 0;
        #pragma unroll
        for (int j = 0; j < 8; ++j) {
            local[j] = bchist[(t * 8 + j) * 8 + k];
            s += local[j];
        }
        ls[t] = s;
        __syncthreads();
        for (int off = 1; off < 256; off <<= 1) {     // inclusive scan
            int u = (t >= off) ? ls[t - off] : 0;
            __syncthreads();
            ls[t] += u;
            __syncthreads();
        }
        int excl  = ls[t] - s;
        int total = ls[255];
        int run = kbase + excl;
        #pragma unroll
        for (int j = 0; j < 8; ++j) {
            bko[(t * 8 + j) * 8 + k] = run;
            run += local[j];
        }
        __syncthreads();
        if (t == 0) { bbase[k] = kbase; kbase += total; }
        __syncthreads();
    }
    if (t == 0) bbase[8] = kbase;   // == N_EDGES
}

// ===================== scans (row_start, dinv) ============================
__global__ void k_scan_block(const int* __restrict__ deg, int* __restrict__ bsum) {
    __shared__ int ls[256];
    int i = blockIdx.x * 256 + threadIdx.x;
    ls[threadIdx.x] = (i < N_NODES) ? deg[i] : 0;
    __syncthreads();
    for (int off = 128; off > 0; off >>= 1) {
        if (threadIdx.x < off) ls[threadIdx.x] += ls[threadIdx.x + off];
        __syncthreads();
    }
    if (threadIdx.x == 0) bsum[blockIdx.x] = ls[0];
}

__global__ void k_scan_top(const int* __restrict__ bsum, int* __restrict__ boff) {
    __shared__ int ls[512];
    int v = (threadIdx.x < NB_SCAN) ? bsum[threadIdx.x] : 0;
    ls[threadIdx.x] = v;
    __syncthreads();
    for (int off = 1; off < 512; off <<= 1) {
        int t = (threadIdx.x >= off) ? ls[threadIdx.x - off] : 0;
        __syncthreads();
        ls[threadIdx.x] += t;
        __syncthreads();
    }
    if (threadIdx.x < NB_SCAN) boff[threadIdx.x] = ls[threadIdx.x] - v; // exclusive
}

__global__ void k_scan_write(const int* __restrict__ deg, const int* __restrict__ boff,
                             int* __restrict__ row_start, float* __restrict__ dinv) {
    __shared__ int ls[256];
    int i = blockIdx.x * 256 + threadIdx.x;
    int v = (i < N_NODES) ? deg[i] : 0;
    ls[threadIdx.x] = v;
    __syncthreads();
    for (int off = 1; off < 256; off <<= 1) {        // inclusive scan
        int t = (threadIdx.x >= off) ? ls[threadIdx.x - off] : 0;
        __syncthreads();
        ls[threadIdx.x] += t;
        __syncthreads();
    }
    if (i < N_NODES) {
        row_start[i] = boff[blockIdx.x] + ls[threadIdx.x] - v;  // exclusive
        dinv[i] = rsqrtf((float)v + 1.0f);                      // +1 self loop
    }
    if (i == N_NODES - 1) row_start[N_NODES] = N_EDGES;
}

// ===================== pass B: scatter edges into buckets ==================
// LDS counters seeded with this block's exact global bases -> zero global
// counter contention; per-block runs are contiguous -> full-line writes.
__global__ __launch_bounds__(256) void k_scat8(
        const int* __restrict__ src, const int* __restrict__ dst,
        const int* __restrict__ bko, unsigned* __restrict__ bkt) {
    __shared__ int lcnt[8];
    if (threadIdx.x < 8) lcnt[threadIdx.x] = bko[blockIdx.x * 8 + threadIdx.x];
    __syncthreads();
    int i0 = blockIdx.x * 256 + threadIdx.x;
    int stride = NBLK * 256;
    for (int i = i0; i < N_EDGES / 4; i += stride) {
        vi4 d = __builtin_nontemporal_load((const vi4*)dst + i);
        vi4 s = __builtin_nontemporal_load((const vi4*)src + i);
        #pragma unroll
        for (int e = 0; e < 4; ++e) {
            int dd = (e == 0) ? d.x : (e == 1) ? d.y : (e == 2) ? d.z : d.w;
            int ss = (e == 0) ? s.x : (e == 1) ? s.y : (e == 2) ? s.z : s.w;
            int k = (unsigned)dd / NPX;
            int pos = atomicAdd(&lcnt[k], 1);
            bkt[pos] = ((unsigned)ss << 14) | (unsigned)(dd - k * NPX);
        }
    }
}

// ===================== pass C: drain bucket k on XCD k -> csr range k ======
__global__ __launch_bounds__(256) void k_fillb(
        const unsigned* __restrict__ bkt, const int* __restrict__ bbase,
        const int* __restrict__ row_start, int* __restrict__ cursor,
        int* __restrict__ csr) {
    int k   = blockIdx.x & 7;
    int lb  = blockIdx.x >> 3;
    int nlb = gridDim.x >> 3;
    int lo  = k * NPX;
    int beg = bbase[k], end = bbase[k + 1];
    for (int i = beg + lb * 256 + threadIdx.x; i < end; i += nlb * 256) {
        unsigned v = bkt[i];
        int s = v >> 14;
        int d = lo + (int)(v & 16383u);
        int p = atomicAdd(&cursor[d], 1);
        csr[row_start[d] + p] = s;
    }
}

// ===================== gather: lane = node, bf16 slice, fused BN stats =====
#define UNPK0(u, k) { acc[k] = __uint_as_float((u) << 16); \
                      acc[k+1] = __uint_as_float((u) & 0xFFFF0000u); }
#define UNPKA(u, k) { acc[k] += __uint_as_float((u) << 16); \
                      acc[k+1] += __uint_as_float((u) & 0xFFFF0000u); }

__global__ __launch_bounds__(256) void k_gath4(
        const int* __restrict__ csr, const int* __restrict__ row_start,
        const float* __restrict__ dinv, const ushort* __restrict__ xsp,
        const float* __restrict__ b, float* __restrict__ hp2,
        float* __restrict__ stats) {
    int tid  = threadIdx.x;
    int lane = tid & 63;
    int widx = tid >> 6;
    int bid  = blockIdx.x;
    int slice = (bid & 7) >> 1;
    int chunk = ((bid >> 3) * 2 + (bid & 1)) * 4 + widx;
    int nchunks = (gridDim.x >> 3) * 8;            // waves per slice
    const ushort* xs = xsp + (size_t)slice * SLICE_U;
    const float*  bs = b + slice * 16;
    float s1[16], s2[16];
    #pragma unroll
    for (int i = 0; i < 16; ++i) { s1[i] = 0.f; s2[i] = 0.f; }

    for (int n0 = chunk * 64; n0 < N_NODES; n0 += nchunks * 64) {
        int n = n0 + lane;
        bool act = n < N_NODES;
        int beg = 0, end = 0;
        float dn = 0.f;
        float acc[16];
        if (act) {
            beg = __builtin_nontemporal_load(row_start + n);
            end = __builtin_nontemporal_load(row_start + n + 1);
            dn  = __builtin_nontemporal_load(dinv + n);
            const uint4* rp = (const uint4*)(xs + (size_t)n * 16);  // self row
            uint4 a = rp[0], c = rp[1];
            UNPK0(a.x, 0)  UNPK0(a.y, 2)  UNPK0(a.z, 4)  UNPK0(a.w, 6)
            UNPK0(c.x, 8)  UNPK0(c.y, 10) UNPK0(c.z, 12) UNPK0(c.w, 14)
        } else {
            #pragma unroll
            for (int i = 0; i < 16; ++i) acc[i] = 0.f;
        }
        int j = beg;
        for (; j + 2 <= end; j += 2) {             // 2 rows in flight
            int s0  = csr[j];
            int s1e = csr[j + 1];
            const uint4* p0 = (const uint4*)(xs + (size_t)s0 * 16);
            const uint4* p1 = (const uint4*)(xs + (size_t)s1e * 16);
            uint4 a0 = p0[0], c0 = p0[1];
            uint4 a1 = p1[0], c1 = p1[1];
            UNPKA(a0.x, 0)  UNPKA(a0.y, 2)  UNPKA(a0.z, 4)  UNPKA(a0.w, 6)
            UNPKA(c0.x, 8)  UNPKA(c0.y, 10) UNPKA(c0.z, 12) UNPKA(c0.w, 14)
            UNPKA(a1.x, 0)  UNPKA(a1.y, 2)  UNPKA(a1.z, 4)  UNPKA(a1.w, 6)
            UNPKA(c1.x, 8)  UNPKA(c1.y, 10) UNPKA(c1.z, 12) UNPKA(c1.w, 14)
        }
        if (j < end) {
            int s0 = csr[j];
            const uint4* p0 = (const uint4*)(xs + (size_t)s0 * 16);
            uint4 a0 = p0[0], c0 = p0[1];
            UNPKA(a0.x, 0)  UNPKA(a0.y, 2)  UNPKA(a0.z, 4)  UNPKA(a0.w, 6)
            UNPKA(c0.x, 8)  UNPKA(c0.y, 10) UNPKA(c0.z, 12) UNPKA(c0.w, 14)
        }
        if (act) {
            #pragma unroll
            for (int sub = 0; sub < 4; ++sub) {
                vf4 hv;
                hv.x = fmaxf(fmaf(dn, acc[4*sub+0], bs[4*sub+0]), 0.f);
                hv.y = fmaxf(fmaf(dn, acc[4*sub+1], bs[4*sub+1]), 0.f);
                hv.z = fmaxf(fmaf(dn, acc[4*sub+2], bs[4*sub+2]), 0.f);
                hv.w = fmaxf(fmaf(dn, acc[4*sub+3], bs[4*sub+3]), 0.f);
                __builtin_nontemporal_store(hv,
                    (vf4*)(hp2 + ((size_t)(slice * 4 + sub) * N_NODES + n) * 4));
                s1[4*sub+0] += hv.x; s2[4*sub+0] = fmaf(hv.x, hv.x, s2[4*sub+0]);
                s1[4*sub+1] += hv.y; s2[4*sub+1] = fmaf(hv.y, hv.y, s2[4*sub+1]);
                s1[4*sub+2] += hv.z; s2[4*sub+2] = fmaf(hv.z, hv.z, s2[4*sub+2]);
                s1[4*sub+3] += hv.w; s2[4*sub+3] = fmaf(hv.w, hv.w, s2[4*sub+3]);
            }
        }
    }

    // wave reduce 32 values, then block reduce via LDS, then atomics
    __shared__ float red[4][32];
    #pragma unroll
    for (int i = 0; i < 16; ++i) {
        float a = s1[i], c = s2[i];
        #pragma unroll
        for (int m = 1; m <= 32; m <<= 1) {
            a += __shfl_xor(a, m);
            c += __shfl_xor(c, m);
        }
        if (lane == 0) { red[widx][i] = a; red[widx][16 + i] = c; }
    }
    __syncthreads();
    if (tid < 32) {
        float v = red[0][tid] + red[1][tid] + red[2][tid] + red[3][tid];
        int ch = slice * 16 + (tid & 15);
        unsafeAtomicAdd(&stats[(tid >> 4) * 64 + ch], v);
    }
}

// ---------------- BN scale/shift precompute (64 threads) -------------------
__global__ void k_scale(const float* __restrict__ stats_in, const float* __restrict__ bnw,
                        const float* __restrict__ bnb, float* __restrict__ scsh) {
    int c = threadIdx.x;   // 0..63
    float mean = stats_in[c] * (1.0f / N_NODES);
    float var  = stats_in[64 + c] * (1.0f / N_NODES) - mean * mean;
    float sc = rsqrtf(var + EPS_BN) * bnw[c];
    scsh[c]      = sc;
    scsh[64 + c] = bnb[c] - mean * sc;
}

// ---------------- BN apply + un-permute ------------------------------------
__global__ __launch_bounds__(256) void k_final_p(
        const float* __restrict__ hp2, const float* __restrict__ scsh,
        float* __restrict__ out) {
    int tid = blockIdx.x * 256 + threadIdx.x;   // over N_NODES*16
    if (tid >= N_NODES * 16) return;
    int q = tid & 15;
    int n = tid >> 4;
    vf4 v  = __builtin_nontemporal_load((const vf4*)hp2 + (size_t)q * N_NODES + n);
    vf4 sc = *(const vf4*)(scsh + q * 4);
    vf4 sh = *(const vf4*)(scsh + 64 + q * 4);
    vf4 o = v * sc + sh;
    __builtin_nontemporal_store(o, (vf4*)out + tid);
}

// ===========================================================================
extern "C" void kernel_launch(void* const* d_in, const int* in_sizes, int n_in,
                              void* d_out, int out_size, void* d_ws, size_t ws_size,
                              hipStream_t stream) {
    const float* x   = (const float*)d_in[0];
    const int*   ei  = (const int*)d_in[1];
    const float* W   = (const float*)d_in[2];
    const float* b   = (const float*)d_in[3];
    const float* bnw = (const float*)d_in[4];
    const float* bnb = (const float*)d_in[5];
    float* out = (float*)d_out;

    const int* src = ei;
    const int* dst = ei + N_EDGES;
    char* ws = (char*)d_ws;

    const size_t SZ_I = 400128;                 // 100000*4 padded
    const size_t OFF_CUR  = SZ_I;
    const size_t OFF_STAT = 2 * SZ_I;           // 512B stat sums
    const size_t OFF_SCSH = 2 * SZ_I + 512;     // 512B scale/shift
    const size_t OFF_DINV = 2 * SZ_I + 1024;
    const size_t OFF_ROW  = 3 * SZ_I + 1024;
    const size_t OFF_BSUM = 4 * SZ_I + 1024;    // 2048
    const size_t OFF_BOFF = 4 * SZ_I + 3072;    // 2048
    const size_t OFF_BCH  = 4 * SZ_I + 5120;    // 64 KB  per-block hist
    const size_t OFF_BKO  = OFF_BCH + 65536;    // 64 KB  per-block offsets
    const size_t OFF_BBS  = OFF_BKO + 65536;    // 256B   bucket bases
    const size_t OFF_CSR  = OFF_BBS + 256;
    const size_t OFF_H    = OFF_CSR + (size_t)N_EDGES * 4;
    const size_t OFF_BKT  = OFF_H;              // buckets alias hp2 (dead early)
    const size_t ZERO_B   = 2 * SZ_I + 512;     // deg, cursor, stats

    ushort* xsp = (ushort*)out;   // 12.8 MB bf16 slice-packed, dead after k_gath4
    const int GEMM_GRID = (N_NODES + MT - 1) / MT;   // 782

    int*      deg       = (int*)ws;
    int*      cursor    = (int*)(ws + OFF_CUR);
    float*    stats     = (float*)(ws + OFF_STAT);
    float*    scsh      = (float*)(ws + OFF_SCSH);
    float*    dinv      = (float*)(ws + OFF_DINV);
    int*      row_start = (int*)(ws + OFF_ROW);
    int*      bsum      = (int*)(ws + OFF_BSUM);
    int*      boff      = (int*)(ws + OFF_BOFF);
    int*      bchist    = (int*)(ws + OFF_BCH);
    int*      bko       = (int*)(ws + OFF_BKO);
    int*      bbase     = (int*)(ws + OFF_BBS);
    int*      csr       = (int*)(ws + OFF_CSR);
    unsigned* bkt       = (unsigned*)(ws + OFF_BKT);
    float*    hp2       = (float*)(ws + OFF_H);

    hipMemsetAsync(d_ws, 0, ZERO_B, stream);  // deg, cursor, stats

    k_hist8     <<<NBLK, 256, 0, stream>>>(dst, deg, bchist);
    k_scanb     <<<1, 256, 0, stream>>>(bchist, bko, bbase);
    k_scan_block<<<NB_SCAN, 256, 0, stream>>>(deg, bsum);
    k_scan_top  <<<1, 512, 0, stream>>>(bsum, boff);
    k_scan_write<<<NB_SCAN, 256, 0, stream>>>(deg, boff, row_start, dinv);
    k_scat8     <<<NBLK, 256, 0, stream>>>(src, dst, bko, bkt);
    k_fillb     <<<2048, 256, 0, stream>>>(bkt, bbase, row_start, cursor, csr);
    k_gemm2     <<<GEMM_GRID, 256, 0, stream>>>(x, W, dinv, xsp);
    k_gath4     <<<1568, 256, 0, stream>>>(csr, row_start, dinv, xsp, b, hp2, stats);
    k_scale     <<<1, 64, 0, stream>>>(stats, bnw, bnb, scsh);
    k_final_p   <<<(N_NODES * 16 + 255) / 256, 256, 0, stream>>>(hp2, scsh, out);
    (void)ws_size;
}

// Round 13
// 294.701 us; speedup vs baseline: 4.5804x; 1.0853x over previous
//
#include <hip/hip_runtime.h>

#define N_NODES 100000
#define N_EDGES 1600000
#define K_DIM   200
#define C_DIM   64
#define EPS_BN  1e-5f
#define NB_SCAN ((N_NODES + 255) / 256)   // 391
#define MT      128                       // gemm rows per block
#define NKB     25                        // 200 / 8 k-blocks
#define SLICE_U ((size_t)N_NODES * 16)    // ushorts per 16-ch bf16 slice
#define NPX     12500                     // nodes per XCD range

// clang ext_vector types: accepted by __builtin_nontemporal_load/store
typedef int      vi4 __attribute__((ext_vector_type(4)));
typedef float    vf4 __attribute__((ext_vector_type(4)));
typedef unsigned vu4 __attribute__((ext_vector_type(4)));

__device__ __forceinline__ ushort f2bf(float f) {
    unsigned u = __float_as_uint(f);
    u = (u + 0x7FFFu + ((u >> 16) & 1u)) >> 16;   // RNE
    return (ushort)u;
}

// ===================== GEMM: 128x64 tile -> pre-scaled bf16 4-slice xsp ====
__global__ __launch_bounds__(256) void k_gemm2(const float* __restrict__ x,
                                               const float* __restrict__ W,
                                               const float* __restrict__ dinv,
                                               ushort* __restrict__ xsp) {
    __shared__ float xT[8][MT];      // 4 KB
    __shared__ float Wt[8][C_DIM];   // 2 KB
    int tid = threadIdx.x;
    int tx = tid & 15;               // channels tx*4..tx*4+3
    int ty = tid >> 4;               // row octet
    int row0 = blockIdx.x * MT;

    int lrow = tid >> 1;
    int lk   = (tid & 1) * 4;
    int grow = row0 + lrow;
    if (grow > N_NODES - 1) grow = N_NODES - 1;
    const float* xp = x + (size_t)grow * K_DIM + lk;
    int wk = tid >> 4;
    int wc = (tid & 15) * 4;

    float acc[8][4];
    #pragma unroll
    for (int i = 0; i < 8; ++i)
        #pragma unroll
        for (int j = 0; j < 4; ++j) acc[i][j] = 0.f;

    float4 xr = *(const float4*)xp;
    float4 wr = {0,0,0,0};
    if (tid < 128) wr = *(const float4*)(W + wk * C_DIM + wc);

    for (int kb = 0; kb < NKB; ++kb) {
        xT[lk + 0][lrow] = xr.x;
        xT[lk + 1][lrow] = xr.y;
        xT[lk + 2][lrow] = xr.z;
        xT[lk + 3][lrow] = xr.w;
        if (tid < 128) *(float4*)&Wt[wk][wc] = wr;
        __syncthreads();
        if (kb < NKB - 1) {
            xr = *(const float4*)(xp + (kb + 1) * 8);
            if (tid < 128) wr = *(const float4*)(W + ((kb + 1) * 8 + wk) * C_DIM + wc);
        }
        #pragma unroll
        for (int k = 0; k < 8; ++k) {
            float4 xa = *(const float4*)&xT[k][ty * 8];
            float4 xb = *(const float4*)&xT[k][ty * 8 + 4];
            float4 wv = *(const float4*)&Wt[k][tx * 4];
            float xv[8] = {xa.x, xa.y, xa.z, xa.w, xb.x, xb.y, xb.z, xb.w};
            #pragma unroll
            for (int i = 0; i < 8; ++i) {
                acc[i][0] = fmaf(xv[i], wv.x, acc[i][0]);
                acc[i][1] = fmaf(xv[i], wv.y, acc[i][1]);
                acc[i][2] = fmaf(xv[i], wv.z, acc[i][2]);
                acc[i][3] = fmaf(xv[i], wv.w, acc[i][3]);
            }
        }
        __syncthreads();
    }
    int sl  = tx >> 2;                 // slice 0..3  (16 channels each)
    int pos = (tx & 3) * 4;            // ushort offset within slice row
    #pragma unroll
    for (int i = 0; i < 8; ++i) {
        int r = row0 + ty * 8 + i;
        if (r < N_NODES) {
            float dv = dinv[r];
            ushort4 o = {f2bf(acc[i][0] * dv), f2bf(acc[i][1] * dv),
                         f2bf(acc[i][2] * dv), f2bf(acc[i][3] * dv)};
            *(ushort4*)(xsp + (size_t)sl * SLICE_U + (size_t)r * 16 + pos) = o;
        }
    }
}

// ===================== CSR build ==========================================
__global__ void k_deg4(const int* __restrict__ dst, int* __restrict__ deg) {
    int tid = blockIdx.x * blockDim.x + threadIdx.x;
    int stride = gridDim.x * blockDim.x;
    for (int i = tid; i < N_EDGES / 4; i += stride) {
        vi4 d = __builtin_nontemporal_load((const vi4*)dst + i);
        atomicAdd(&deg[d.x], 1);
        atomicAdd(&deg[d.y], 1);
        atomicAdd(&deg[d.z], 1);
        atomicAdd(&deg[d.w], 1);
    }
}

__global__ void k_scan_block(const int* __restrict__ deg, int* __restrict__ bsum) {
    __shared__ int ls[256];
    int i = blockIdx.x * 256 + threadIdx.x;
    ls[threadIdx.x] = (i < N_NODES) ? deg[i] : 0;
    __syncthreads();
    for (int off = 128; off > 0; off >>= 1) {
        if (threadIdx.x < off) ls[threadIdx.x] += ls[threadIdx.x + off];
        __syncthreads();
    }
    if (threadIdx.x == 0) bsum[blockIdx.x] = ls[0];
}

__global__ void k_scan_top(const int* __restrict__ bsum, int* __restrict__ boff) {
    __shared__ int ls[512];
    int v = (threadIdx.x < NB_SCAN) ? bsum[threadIdx.x] : 0;
    ls[threadIdx.x] = v;
    __syncthreads();
    for (int off = 1; off < 512; off <<= 1) {
        int t = (threadIdx.x >= off) ? ls[threadIdx.x - off] : 0;
        __syncthreads();
        ls[threadIdx.x] += t;
        __syncthreads();
    }
    if (threadIdx.x < NB_SCAN) boff[threadIdx.x] = ls[threadIdx.x] - v; // exclusive
}

__global__ void k_scan_write(const int* __restrict__ deg, const int* __restrict__ boff,
                             int* __restrict__ row_start, float* __restrict__ dinv) {
    __shared__ int ls[256];
    int i = blockIdx.x * 256 + threadIdx.x;
    int v = (i < N_NODES) ? deg[i] : 0;
    ls[threadIdx.x] = v;
    __syncthreads();
    for (int off = 1; off < 256; off <<= 1) {        // inclusive scan
        int t = (threadIdx.x >= off) ? ls[threadIdx.x - off] : 0;
        __syncthreads();
        ls[threadIdx.x] += t;
        __syncthreads();
    }
    if (i < N_NODES) {
        row_start[i] = boff[blockIdx.x] + ls[threadIdx.x] - v;  // exclusive
        dinv[i] = rsqrtf((float)v + 1.0f);                      // +1 self loop
    }
    if (i == N_NODES - 1) row_start[N_NODES] = N_EDGES;
}

// XCD-range-partitioned fill: block bid&7 handles dst in [lo, lo+NPX).
__global__ __launch_bounds__(256) void k_fill8(
        const int* __restrict__ src, const int* __restrict__ dst,
        const int* __restrict__ row_start, int* __restrict__ cursor,
        int* __restrict__ csr) {
    unsigned lo = (blockIdx.x & 7) * NPX;
    int i0 = (blockIdx.x >> 3) * 256 + threadIdx.x;
    int stride = (gridDim.x >> 3) * 256;
    for (int i = i0; i < N_EDGES / 4; i += stride) {
        vi4 d = __builtin_nontemporal_load((const vi4*)dst + i);
        bool mx = (unsigned)(d.x - lo) < NPX;
        bool my = (unsigned)(d.y - lo) < NPX;
        bool mz = (unsigned)(d.z - lo) < NPX;
        bool mw = (unsigned)(d.w - lo) < NPX;
        if (mx | my | mz | mw) {               // load src only when needed (41%)
            vi4 s = __builtin_nontemporal_load((const vi4*)src + i);
            if (mx) { int p = atomicAdd(&cursor[d.x], 1); csr[row_start[d.x] + p] = s.x; }
            if (my) { int p = atomicAdd(&cursor[d.y], 1); csr[row_start[d.y] + p] = s.y; }
            if (mz) { int p = atomicAdd(&cursor[d.z], 1); csr[row_start[d.z] + p] = s.z; }
            if (mw) { int p = atomicAdd(&cursor[d.w], 1); csr[row_start[d.w] + p] = s.w; }
        }
    }
}

// ===================== gather: lane = node, bf16 slice, bf16 h out =========
// csr loads CACHED (L1 reuse); nt on one-time streams (row_start/dinv/h).
#define UNPK0(u, k) { acc[k] = __uint_as_float((u) << 16); \
                      acc[k+1] = __uint_as_float((u) & 0xFFFF0000u); }
#define UNPKA(u, k) { acc[k] += __uint_as_float((u) << 16); \
                      acc[k+1] += __uint_as_float((u) & 0xFFFF0000u); }

__global__ __launch_bounds__(256) void k_gath4(
        const int* __restrict__ csr, const int* __restrict__ row_start,
        const float* __restrict__ dinv, const ushort* __restrict__ xsp,
        const float* __restrict__ b, ushort* __restrict__ hp2,
        float* __restrict__ stats) {
    int tid  = threadIdx.x;
    int lane = tid & 63;
    int widx = tid >> 6;
    int bid  = blockIdx.x;
    int slice = (bid & 7) >> 1;
    int chunk = ((bid >> 3) * 2 + (bid & 1)) * 4 + widx;
    int nchunks = (gridDim.x >> 3) * 8;            // waves per slice
    const ushort* xs = xsp + (size_t)slice * SLICE_U;
    const float*  bs = b + slice * 16;
    float s1[16], s2[16];
    #pragma unroll
    for (int i = 0; i < 16; ++i) { s1[i] = 0.f; s2[i] = 0.f; }

    for (int n0 = chunk * 64; n0 < N_NODES; n0 += nchunks * 64) {
        int n = n0 + lane;
        bool act = n < N_NODES;
        int beg = 0, end = 0;
        float dn = 0.f;
        float acc[16];
        if (act) {
            beg = __builtin_nontemporal_load(row_start + n);
            end = __builtin_nontemporal_load(row_start + n + 1);
            dn  = __builtin_nontemporal_load(dinv + n);
            const uint4* rp = (const uint4*)(xs + (size_t)n * 16);  // self row
            uint4 a = rp[0], c = rp[1];
            UNPK0(a.x, 0)  UNPK0(a.y, 2)  UNPK0(a.z, 4)  UNPK0(a.w, 6)
            UNPK0(c.x, 8)  UNPK0(c.y, 10) UNPK0(c.z, 12) UNPK0(c.w, 14)
        } else {
            #pragma unroll
            for (int i = 0; i < 16; ++i) acc[i] = 0.f;
        }
        int j = beg;
        for (; j + 2 <= end; j += 2) {             // 2 rows in flight
            int s0  = csr[j];
            int s1e = csr[j + 1];
            const uint4* p0 = (const uint4*)(xs + (size_t)s0 * 16);
            const uint4* p1 = (const uint4*)(xs + (size_t)s1e * 16);
            uint4 a0 = p0[0], c0 = p0[1];
            uint4 a1 = p1[0], c1 = p1[1];
            UNPKA(a0.x, 0)  UNPKA(a0.y, 2)  UNPKA(a0.z, 4)  UNPKA(a0.w, 6)
            UNPKA(c0.x, 8)  UNPKA(c0.y, 10) UNPKA(c0.z, 12) UNPKA(c0.w, 14)
            UNPKA(a1.x, 0)  UNPKA(a1.y, 2)  UNPKA(a1.z, 4)  UNPKA(a1.w, 6)
            UNPKA(c1.x, 8)  UNPKA(c1.y, 10) UNPKA(c1.z, 12) UNPKA(c1.w, 14)
        }
        if (j < end) {
            int s0 = csr[j];
            const uint4* p0 = (const uint4*)(xs + (size_t)s0 * 16);
            uint4 a0 = p0[0], c0 = p0[1];
            UNPKA(a0.x, 0)  UNPKA(a0.y, 2)  UNPKA(a0.z, 4)  UNPKA(a0.w, 6)
            UNPKA(c0.x, 8)  UNPKA(c0.y, 10) UNPKA(c0.z, 12) UNPKA(c0.w, 14)
        }
        if (act) {
            unsigned pk[8];
            #pragma unroll
            for (int i2 = 0; i2 < 8; ++i2) {
                float lo = fmaxf(fmaf(dn, acc[2*i2+0], bs[2*i2+0]), 0.f);
                float hi = fmaxf(fmaf(dn, acc[2*i2+1], bs[2*i2+1]), 0.f);
                s1[2*i2+0] += lo; s2[2*i2+0] = fmaf(lo, lo, s2[2*i2+0]);
                s1[2*i2+1] += hi; s2[2*i2+1] = fmaf(hi, hi, s2[2*i2+1]);
                pk[i2] = (unsigned)f2bf(lo) | ((unsigned)f2bf(hi) << 16);
            }
            vu4 w0 = {pk[0], pk[1], pk[2], pk[3]};
            vu4 w1 = {pk[4], pk[5], pk[6], pk[7]};
            ushort* hb = hp2 + ((size_t)slice * N_NODES + (size_t)n) * 16;
            __builtin_nontemporal_store(w0, (vu4*)hb);
            __builtin_nontemporal_store(w1, (vu4*)(hb + 8));
        }
    }

    // wave reduce 32 values, then block reduce via LDS, then atomics
    __shared__ float red[4][32];
    #pragma unroll
    for (int i = 0; i < 16; ++i) {
        float a = s1[i], c = s2[i];
        #pragma unroll
        for (int m = 1; m <= 32; m <<= 1) {
            a += __shfl_xor(a, m);
            c += __shfl_xor(c, m);
        }
        if (lane == 0) { red[widx][i] = a; red[widx][16 + i] = c; }
    }
    __syncthreads();
    if (tid < 32) {
        float v = red[0][tid] + red[1][tid] + red[2][tid] + red[3][tid];
        int ch = slice * 16 + (tid & 15);
        unsafeAtomicAdd(&stats[(tid >> 4) * 64 + ch], v);
    }
}

// ---------------- BN scale/shift precompute (64 threads) -------------------
__global__ void k_scale(const float* __restrict__ stats_in, const float* __restrict__ bnw,
                        const float* __restrict__ bnb, float* __restrict__ scsh) {
    int c = threadIdx.x;   // 0..63
    float mean = stats_in[c] * (1.0f / N_NODES);
    float var  = stats_in[64 + c] * (1.0f / N_NODES) - mean * mean;
    float sc = rsqrtf(var + EPS_BN) * bnw[c];
    scsh[c]      = sc;
    scsh[64 + c] = bnb[c] - mean * sc;
}

// ---------------- BN apply + unpack bf16 h + un-permute --------------------
__global__ __launch_bounds__(256) void k_final_p(
        const ushort* __restrict__ hp2, const float* __restrict__ scsh,
        float* __restrict__ out) {
    int tid = blockIdx.x * 256 + threadIdx.x;   // over N_NODES*8
    if (tid >= N_NODES * 8) return;
    int half = tid & 7;                         // 8 channels per thread
    int n    = tid >> 3;
    int slice = half >> 1, sub = half & 1;
    vu4 v = __builtin_nontemporal_load(
        (const vu4*)(hp2 + ((size_t)slice * N_NODES + (size_t)n) * 16 + sub * 8));
    int cb = slice * 16 + sub * 8;
    vf4 sc0 = *(const vf4*)(scsh + cb);
    vf4 sc1 = *(const vf4*)(scsh + cb + 4);
    vf4 sh0 = *(const vf4*)(scsh + 64 + cb);
    vf4 sh1 = *(const vf4*)(scsh + 64 + cb + 4);
    vf4 h0, h1;
    h0.x = __uint_as_float(v.x << 16); h0.y = __uint_as_float(v.x & 0xFFFF0000u);
    h0.z = __uint_as_float(v.y << 16); h0.w = __uint_as_float(v.y & 0xFFFF0000u);
    h1.x = __uint_as_float(v.z << 16); h1.y = __uint_as_float(v.z & 0xFFFF0000u);
    h1.z = __uint_as_float(v.w << 16); h1.w = __uint_as_float(v.w & 0xFFFF0000u);
    vf4 o0 = h0 * sc0 + sh0;
    vf4 o1 = h1 * sc1 + sh1;
    float* op = out + (size_t)n * C_DIM + cb;
    __builtin_nontemporal_store(o0, (vf4*)op);
    __builtin_nontemporal_store(o1, (vf4*)(op + 4));
}

// ===========================================================================
extern "C" void kernel_launch(void* const* d_in, const int* in_sizes, int n_in,
                              void* d_out, int out_size, void* d_ws, size_t ws_size,
                              hipStream_t stream) {
    const float* x   = (const float*)d_in[0];
    const int*   ei  = (const int*)d_in[1];
    const float* W   = (const float*)d_in[2];
    const float* b   = (const float*)d_in[3];
    const float* bnw = (const float*)d_in[4];
    const float* bnb = (const float*)d_in[5];
    float* out = (float*)d_out;

    const int* src = ei;
    const int* dst = ei + N_EDGES;
    char* ws = (char*)d_ws;

    const size_t SZ_I = 400128;                 // 100000*4 padded
    const size_t OFF_CUR  = SZ_I;
    const size_t OFF_STAT = 2 * SZ_I;           // 512B stat sums
    const size_t OFF_SCSH = 2 * SZ_I + 512;     // 512B scale/shift
    const size_t OFF_DINV = 2 * SZ_I + 1024;
    const size_t OFF_ROW  = 3 * SZ_I + 1024;
    const size_t OFF_BSUM = 4 * SZ_I + 1024;
    const size_t OFF_BOFF = 4 * SZ_I + 3072;
    const size_t OFF_CSR  = 4 * SZ_I + 5120;
    const size_t OFF_H    = OFF_CSR + (size_t)N_EDGES * 4;   // 12.8 MB bf16 h
    const size_t ZERO_B   = 2 * SZ_I + 512;     // deg, cursor, stats

    ushort* xsp = (ushort*)out;   // 12.8 MB bf16 slice-packed, dead after k_gath4
    const int GEMM_GRID = (N_NODES + MT - 1) / MT;   // 782

    int*    deg       = (int*)ws;
    int*    cursor    = (int*)(ws + OFF_CUR);
    float*  stats     = (float*)(ws + OFF_STAT);
    float*  scsh      = (float*)(ws + OFF_SCSH);
    float*  dinv      = (float*)(ws + OFF_DINV);
    int*    row_start = (int*)(ws + OFF_ROW);
    int*    bsum      = (int*)(ws + OFF_BSUM);
    int*    boff      = (int*)(ws + OFF_BOFF);
    int*    csr       = (int*)(ws + OFF_CSR);
    ushort* hp2       = (ushort*)(ws + OFF_H);

    hipMemsetAsync(d_ws, 0, ZERO_B, stream);  // deg, cursor, stat sums

    k_deg4      <<<1024, 256, 0, stream>>>(dst, deg);
    k_scan_block<<<NB_SCAN, 256, 0, stream>>>(deg, bsum);
    k_scan_top  <<<1, 512, 0, stream>>>(bsum, boff);
    k_scan_write<<<NB_SCAN, 256, 0, stream>>>(deg, boff, row_start, dinv);
    k_fill8     <<<2048, 256, 0, stream>>>(src, dst, row_start, cursor, csr);
    k_gemm2     <<<GEMM_GRID, 256, 0, stream>>>(x, W, dinv, xsp);
    k_gath4     <<<1568, 256, 0, stream>>>(csr, row_start, dinv, xsp, b, hp2, stats);
    k_scale     <<<1, 64, 0, stream>>>(stats, bnw, bnb, scsh);
    k_final_p   <<<(N_NODES * 8 + 255) / 256, 256, 0, stream>>>(hp2, scsh, out);
    (void)ws_size;
}